// Round 4
// baseline (283.837 us; speedup 1.0000x reference)
//
#include <hip/hip_runtime.h>

#define IMG 512
#define OUT_C 64         // output cols per block
#define STRIP_R 128      // output rows per block
#define CHUNK 16         // output rows per iteration
#define NITER (STRIP_R / CHUNK)
#define HALO 5
#define IN_C 74          // OUT_C + 2*HALO
#define CPAD 80          // padded cols = 5 MFMA col-tiles of 16
#define NVTILE 5
#define VS 88            // vbuf row stride in halfs (176B, bank-staggered)
#define NT 256
#define NSLOTS 64

typedef _Float16 f16x8 __attribute__((ext_vector_type(8)));
typedef _Float16 f16x4 __attribute__((ext_vector_type(4)));
typedef float    f32x4 __attribute__((ext_vector_type(4)));

static constexpr float GWf[11] = {
    0.00102838f, 0.00759876f, 0.03600077f, 0.10936053f, 0.21300556f,
    0.26601170f, 0.21300556f, 0.10936053f, 0.03600077f, 0.00759876f,
    0.00102838f };

// Banded weight fragments. Position-wise contraction D[i][j] =
// sum_{g,b} Afrag[i;g,b]*Bfrag[j;g,b] is HW-verified by R2/R3 (absmax=0),
// so explicit (g,b)<->k placement is safe regardless of internal k-perm.
// WV (vertical A): W[i][k] = w[k-i-3], K-window = rows [yo-8, yo+24).
// WH (horizontal B): W[k][j] = w[k-j],  K-window = V cols [m*16, m*16+32).
struct WTab { alignas(16) _Float16 v[4][16][8]; };
static constexpr WTab make_wtab(int off) {
    WTab t{};
    for (int g = 0; g < 4; ++g)
        for (int j = 0; j < 16; ++j)
            for (int b = 0; b < 8; ++b) {
                const int d = 8 * g + b - j - off;
                t.v[g][j][b] = (d >= 0 && d <= 10) ? (_Float16)GWf[d]
                                                   : (_Float16)0.f;
            }
    return t;
}
__device__ constexpr WTab WV = make_wtab(3);
__device__ constexpr WTab WH = make_wtab(0);

// chbuf: rolling 32-row window, column-major [ch][col][32]. Input row gr
// lives in 16B slot (gr>>3)&3, XORed with ((col>>1)&3) for bank spread.
// vb: vertical-conv output, row-major [ch][16][VS]. Separate region
// (window persists across iterations -> no aliasing).
struct SMem {
    _Float16 ch[4][CPAD][32];    // 20480 B
    _Float16 vb[4][CHUNK][VS];   // 11264 B
    float red[4];
};                               // 31760 B -> 5 blocks/CU

__device__ __forceinline__ void load4(int c, int gr0, int c0, size_t pbase,
                                      const float* __restrict__ den,
                                      const float* __restrict__ cln,
                                      float xs[4], float ys[4]) {
    const int gc = c0 - HALO + c;
    const bool colok = ((unsigned)gc < IMG) && (c < IN_C);
#pragma unroll
    for (int rr = 0; rr < 4; ++rr) {
        const int gr = gr0 + rr;
        float x = 0.f, y = 0.f;
        if (colok && ((unsigned)gr < IMG)) {
            const size_t idx = pbase + (size_t)gr * IMG + gc;
            x = den[idx]; y = cln[idx];
        }
        xs[rr] = x; ys[rr] = y;
    }
}

__device__ __forceinline__ void store4(int c, int gr0, const float xs[4],
                                       const float ys[4], SMem* sm) {
    union { f16x4 v[4]; _Float16 h[16]; } st;
#pragma unroll
    for (int rr = 0; rr < 4; ++rr) {
        const float x = fminf(fmaxf(xs[rr], 0.f), 1.f);  // v_med3_f32
        const float y = fminf(fmaxf(ys[rr], 0.f), 1.f);
        st.h[rr]      = (_Float16)x;
        st.h[4 + rr]  = (_Float16)y;
        st.h[8 + rr]  = (_Float16)fmaf(x, x, y * y);
        st.h[12 + rr] = (_Float16)(x * y);
    }
    const int s    = (((gr0 + 512) >> 3) & 3) ^ ((c >> 1) & 3);
    const int half = (gr0 >> 2) & 1;                     // rows 0-3 / 4-7 of slot
#pragma unroll
    for (int ch = 0; ch < 4; ++ch)
        *reinterpret_cast<f16x4*>(&sm->ch[ch][c][s * 8 + half * 4]) = st.v[ch];
}

__global__ __launch_bounds__(NT, 5)
void ssim_mfma(const float* __restrict__ den, const float* __restrict__ cln,
               double* __restrict__ slots) {
    __shared__ SMem sm;

    const int t    = threadIdx.x;
    const int lane = t & 63;
    const int w    = t >> 6;
    const int fj   = lane & 15;   // MFMA i/j index
    const int fg   = lane >> 4;   // MFMA k-group

    // XCD-chunked swizzle (grid % 8 == 0): neighbors share column halos.
    const int bid = blockIdx.x;
    int vid = bid;
    {
        const int chunk = gridDim.x >> 3;
        vid = (bid & 7) * chunk + (bid >> 3);
    }
    const int rs    = vid & 3;          // 4 row strips of 128
    const int cs    = (vid >> 2) & 7;   // 8 col strips of 64
    const int plane = vid >> 5;         // 96 planes
    const int c0 = cs * OUT_C;
    const int y0 = rs * STRIP_R;
    const size_t pbase = (size_t)plane * (IMG * IMG);

    const f16x8 wv = *reinterpret_cast<const f16x8*>(WV.v[fg][fj]);
    const f16x8 wh = *reinterpret_cast<const f16x8*>(WH.v[fg][fj]);
    const f32x4 zero4 = {0.f, 0.f, 0.f, 0.f};

    // ---- prologue: fill window rows [y0-8, y0+24) = 640 quarter-tasks ----
#pragma unroll
    for (int base = 0; base < 640; base += NT) {
        const int task = base + t;
        if (task < 640) {
            const int c  = task % CPAD;
            const int q  = task / CPAD;          // 0..7
            const int g0 = y0 - 8 + 4 * q;
            float xs[4], ys[4];
            load4(c, g0, c0, pbase, den, cln, xs, ys);
            store4(c, g0, xs, ys, &sm);
        }
    }
    __syncthreads();

    float sacc = 0.f;
    for (int it = 0; it < NITER; ++it) {
        const int yo = y0 + CHUNK * it;
        const bool pf = (it < NITER - 1);

        // ---- L: prefetch next chunk rows [yo+24, yo+40) into registers ----
        // 320 quarter-tasks: task t (all threads) + task 256+t (t<64).
        const int c_0 = t % CPAD, q_0 = t / CPAD;
        const int g0_ = yo + 24 + 4 * q_0;
        const int c_1 = (NT + t) % CPAD, q_1 = (NT + t) / CPAD;
        const int g1_ = yo + 24 + 4 * q_1;
        float px0[4], py0[4], px1[4], py1[4];
        if (pf)           load4(c_0, g0_, c0, pbase, den, cln, px0, py0);
        if (pf && t < 64) load4(c_1, g1_, c0, pbase, den, cln, px1, py1);

        // ---- A: vertical conv via MFMA (reads rotated window) ----
        // D = WV(16x32) * window(32 x 16cols); 5 tiles * 4ch = 20, 5/wave
        const int ph = (((yo - 8) + 512) >> 3) & 3;   // slot of logical k-group 0
        f32x4 acc[NVTILE];
#pragma unroll
        for (int n = 0; n < NVTILE; ++n) {
            const int tau  = NVTILE * w + n;
            const int tile = tau >> 2;
            const int ch   = tau & 3;
            const int colp = tile * 16 + fj;
            const int s    = ((ph + fg) & 3) ^ ((colp >> 1) & 3);
            const f16x8 bf = *reinterpret_cast<const f16x8*>(
                &sm.ch[ch][colp][s * 8]);
            acc[n] = __builtin_amdgcn_mfma_f32_16x16x32_f16(wv, bf, zero4,
                                                            0, 0, 0);
        }
        __syncthreads();   // window reads done; vb free (prev C consumed it)

        // ---- B: write prefetched rows into vacated slots; store vb ----
        if (pf) {
            store4(c_0, g0_, px0, py0, &sm);
            if (t < 64) store4(c_1, g1_, px1, py1, &sm);
        }
#pragma unroll
        for (int n = 0; n < NVTILE; ++n) {
            const int tau  = NVTILE * w + n;
            const int tile = tau >> 2;
            const int ch   = tau & 3;
#pragma unroll
            for (int b = 0; b < 4; ++b)
                sm.vb[ch][4 * fg + b][tile * 16 + fj] = (_Float16)acc[n][b];
        }
        __syncthreads();

        // ---- C: horizontal conv via MFMA + SSIM (reads vb only) ----
        {
            const int m = w;
            f32x4 d[4];
#pragma unroll
            for (int ch = 0; ch < 4; ++ch) {
                const f16x8 af = *reinterpret_cast<const f16x8*>(
                    &sm.vb[ch][fj][m * 16 + 8 * fg]);
                d[ch] = __builtin_amdgcn_mfma_f32_16x16x32_f16(af, wh, zero4,
                                                               0, 0, 0);
            }
#pragma unroll
            for (int b = 0; b < 4; ++b) {
                const float C1 = 1e-4f, C2 = 9e-4f;
                const float mu1 = d[0][b], mu2 = d[1][b];
                const float qb  = d[2][b], pb  = d[3][b];
                const float mu1s = mu1 * mu1, mu2s = mu2 * mu2,
                            mu12 = mu1 * mu2;
                const float ssum = qb - mu1s - mu2s;
                const float s12  = pb - mu12;
                const float num = fmaf(2.f, mu12, C1) * fmaf(2.f, s12, C2);
                const float dnm = (mu1s + mu2s + C1) * (ssum + C2);
                sacc = fmaf(num, __builtin_amdgcn_rcpf(dnm), sacc);
            }
        }
    }

    // ---- block reduction, one f64 atomic per block into a hashed slot ----
#pragma unroll
    for (int off = 32; off > 0; off >>= 1)
        sacc += __shfl_down(sacc, off, 64);
    if (lane == 0) sm.red[w] = sacc;
    __syncthreads();
    if (t == 0) {
        const float s = sm.red[0] + sm.red[1] + sm.red[2] + sm.red[3];
        atomicAdd(&slots[(size_t)(bid & (NSLOTS - 1)) * 8], (double)s);
    }
}

__global__ void ssim_finalize(const double* __restrict__ slots,
                              float* __restrict__ out, double inv_n) {
    double s = 0.0;
    for (int i = 0; i < NSLOTS; ++i) s += slots[i * 8];
    out[0] = 1.0f - (float)(s * inv_n);
}

extern "C" void kernel_launch(void* const* d_in, const int* in_sizes, int n_in,
                              void* d_out, int out_size, void* d_ws,
                              size_t ws_size, hipStream_t stream) {
    const float* den = (const float*)d_in[0];
    const float* cln = (const float*)d_in[1];
    float* out = (float*)d_out;
    double* slots = (double*)d_ws;

    hipMemsetAsync(d_ws, 0, NSLOTS * 64, stream);

    const int n = in_sizes[0];                  // 32*3*512*512 elements
    const int planes = n / (IMG * IMG);         // 96
    dim3 grid(planes * (IMG / STRIP_R) * (IMG / OUT_C));   // 96*4*8 = 3072
    ssim_mfma<<<grid, NT, 0, stream>>>(den, cln, slots);
    ssim_finalize<<<1, 1, 0, stream>>>(slots, out, 1.0 / (double)n);
}